// Round 7
// baseline (315.634 us; speedup 1.0000x reference)
//
#include <hip/hip_runtime.h>
#include <hip/hip_bf16.h>

#define B_   8
#define C1_  256
#define C2_  256
#define Cm_  128    // C_ = C2/2
#define H_   80
#define W_   80
#define HW_  6400
#define CN_  1152   // C_ * 9
#define EPS_ 1e-5f

#define CH_   32    // channels per K-chunk in fused kernel
#define NCHK_ 4     // number of chunks (128/32)
#define KCH_  288   // K per chunk = CH_*9
#define VSTR_ 296   // vbuf row stride in shorts (592 B: 16B-aligned, bank-uniform)

typedef __attribute__((ext_vector_type(8))) short bf16x8;
typedef __attribute__((ext_vector_type(4))) float f32x4;

__device__ inline unsigned short f2bf(float f) {
  union { float f; unsigned int u; } v; v.f = f;
  unsigned int u = v.u;
  unsigned int r = (u + 0x7FFFu + ((u >> 16) & 1u)) >> 16;
  return (unsigned short)r;
}
__device__ inline float bf2f(unsigned short s) {
  union { unsigned int u; float f; } v; v.u = ((unsigned int)s) << 16;
  return v.f;
}

// ---------------- Kernel 0: prep — Wc->bf16, BN2 scale/shift ----------------
__global__ __launch_bounds__(256) void k0_prep(
    const float* __restrict__ Wc, const float* __restrict__ bc,
    const float* __restrict__ g2, const float* __restrict__ b2,
    const float* __restrict__ m2, const float* __restrict__ v2,
    unsigned short* __restrict__ Wcb, float* __restrict__ A2,
    float* __restrict__ B2) {
  int idx = blockIdx.x * 256 + threadIdx.x;
  if (idx < C2_ * CN_) Wcb[idx] = f2bf(Wc[idx]);
  if (idx < C2_) {
    float s = g2[idx] * rsqrtf(v2[idx] + EPS_);
    A2[idx] = s;
    B2[idx] = (bc[idx] - m2[idx]) * s + b2[idx];
  }
}

// ---------------- Kernel 1: h = SiLU(BN1(W1 @ x)), bf16 out -----------------
// Register-tiled fp32 GEMM: block tile M=128 x N=128, K-chunk 16 via LDS,
// thread tile 8x8. grid: (HW/128, B), block 256.
__global__ __launch_bounds__(256) void k1_cv1(
    const float* __restrict__ x, const float* __restrict__ W1,
    const float* __restrict__ g1, const float* __restrict__ b1,
    const float* __restrict__ m1, const float* __restrict__ v1,
    unsigned short* __restrict__ h) {
  __shared__ float ws[16][128];   // W1^T chunk: [kk][m]
  __shared__ float xs[16][128];   // x chunk:    [kk][n]
  const int b   = blockIdx.y;
  const int hw0 = blockIdx.x * 128;
  const int t   = threadIdx.x;
  const int tn  = t & 15;         // n-group
  const int tm  = t >> 4;         // m-group

  float acc[8][8];
#pragma unroll
  for (int i = 0; i < 8; ++i)
#pragma unroll
    for (int j = 0; j < 8; ++j) acc[i][j] = 0.f;

  const int m_l = t & 127;        // staging: lane-consecutive m / n
  for (int c0 = 0; c0 < C1_; c0 += 16) {
#pragma unroll
    for (int i = 0; i < 8; ++i) {
      int idx = t + i * 256;
      int kk = idx >> 7;          // thread reads 8 elems of one W1 row
      ws[kk][m_l] = W1[m_l * C1_ + c0 + kk];
    }
#pragma unroll
    for (int i = 0; i < 8; ++i) {
      int idx = t + i * 256;
      int kk = idx >> 7;
      xs[kk][m_l] = x[((size_t)b * C1_ + c0 + kk) * HW_ + hw0 + m_l];
    }
    __syncthreads();
#pragma unroll
    for (int kk = 0; kk < 16; ++kk) {
      float av[8], bv[8];
      *reinterpret_cast<float4*>(&av[0]) = *reinterpret_cast<const float4*>(&ws[kk][tm * 8]);
      *reinterpret_cast<float4*>(&av[4]) = *reinterpret_cast<const float4*>(&ws[kk][tm * 8 + 4]);
      *reinterpret_cast<float4*>(&bv[0]) = *reinterpret_cast<const float4*>(&xs[kk][tn * 8]);
      *reinterpret_cast<float4*>(&bv[4]) = *reinterpret_cast<const float4*>(&xs[kk][tn * 8 + 4]);
#pragma unroll
      for (int i = 0; i < 8; ++i)
#pragma unroll
        for (int j = 0; j < 8; ++j)
          acc[i][j] = fmaf(av[i], bv[j], acc[i][j]);
    }
    __syncthreads();
  }

  // epilogue: BN1 + SiLU, packed bf16 stores (16 B per row of 8)
#pragma unroll
  for (int i = 0; i < 8; ++i) {
    int o = tm * 8 + i;
    float s  = g1[o] * rsqrtf(v1[o] + EPS_);
    float sh = b1[o] - m1[o] * s;
    unsigned short pk[8];
#pragma unroll
    for (int j = 0; j < 8; ++j) {
      float val = fmaf(acc[i][j], s, sh);
      float sig = 1.f / (1.f + __expf(-val));
      pk[j] = f2bf(val * sig);
    }
    uint4* dst = reinterpret_cast<uint4*>(
        h + ((size_t)b * Cm_ + o) * HW_ + hw0 + tn * 8);
    *dst = *reinterpret_cast<const uint4*>(pk);
  }
}

// ---------------- Kernel 2 (fused): weights+softmax+GEMM+epilogue -----------
// grid: (H, B), block 256 (4 waves). Block computes out[:, y, 0:80] for batch b.
// Per 32-channel chunk: stage h halo -> weights/softmax into LDS vbuf ->
// MFMA K-slice (K=288) accumulated in registers. 4 chunks = full K=1152.
__global__ __launch_bounds__(256) void k2f(
    const unsigned short* __restrict__ h,
    const float* __restrict__ Wg, const float* __restrict__ bg,
    const float* __restrict__ gg, const float* __restrict__ bgw,
    const float* __restrict__ mg, const float* __restrict__ vg,
    const unsigned short* __restrict__ Wcb,
    const float* __restrict__ A2, const float* __restrict__ B2,
    const float* __restrict__ x, float* __restrict__ out) {
  __shared__ unsigned short ht[CH_ * 3 * 82];    // halo: [c][r][xx], 15744 B
  __shared__ unsigned short vbuf[80][VSTR_];     // weighted patches [px][k], 47360 B

  const int b   = blockIdx.y;
  const int y   = blockIdx.x;
  const int t   = threadIdx.x;
  const int w   = __builtin_amdgcn_readfirstlane(t >> 6);
  const int l   = t & 63;
  const int l15 = l & 15;
  const int lhi = l >> 4;

  f32x4 acc[4][5];
#pragma unroll
  for (int i = 0; i < 4; ++i)
#pragma unroll
    for (int nf = 0; nf < 5; ++nf) acc[i][nf] = (f32x4)0.f;

  for (int ch = 0; ch < NCHK_; ++ch) {
    // ---- stage h halo for this channel chunk (zero-padded) ----
    for (int idx = t; idx < CH_ * 3 * 82; idx += 256) {
      int c   = idx / 246;          // 246 = 3*82
      int rem = idx - c * 246;
      int r   = rem / 82;
      int xx  = rem - r * 82;
      int gy  = y + r - 1;
      int gx  = xx - 1;
      unsigned short v = 0;
      if ((unsigned)gy < (unsigned)H_ && (unsigned)gx < (unsigned)W_)
        v = h[((size_t)b * Cm_ + ch * CH_ + c) * HW_ + gy * W_ + gx];
      ht[idx] = v;
    }
    __syncthreads();

    // ---- weights: 32 ch x 80 px items; 9->9 mix + BN + softmax -> vbuf ----
#pragma unroll
    for (int it = 0; it < 10; ++it) {
      int id  = it * 256 + t;       // 0..2559
      int c_l = id / 80;            // 0..31
      int px  = id - c_l * 80;      // 0..79
      int cg  = ch * CH_ + c_l;
      float p[9];
#pragma unroll
      for (int i = 0; i < 3; ++i)
#pragma unroll
        for (int j = 0; j < 3; ++j)
          p[i * 3 + j] = bf2f(ht[(c_l * 3 + i) * 82 + px + j]);
      float wv[9];
#pragma unroll
      for (int o = 0; o < 9; ++o) {
        float a = bg[cg * 9 + o];
#pragma unroll
        for (int i = 0; i < 9; ++i)
          a = fmaf(Wg[cg * 81 + o * 9 + i], p[i], a);
        float s = gg[cg * 9 + o] * rsqrtf(vg[cg * 9 + o] + EPS_);
        wv[o] = (a - mg[cg * 9 + o]) * s + bgw[cg * 9 + o];
      }
      float mx = wv[0];
#pragma unroll
      for (int o = 1; o < 9; ++o) mx = fmaxf(mx, wv[o]);
      float sum = 0.f;
#pragma unroll
      for (int o = 0; o < 9; ++o) { wv[o] = __expf(wv[o] - mx); sum += wv[o]; }
      float inv = 1.f / sum;
#pragma unroll
      for (int n = 0; n < 9; ++n)
        vbuf[px][c_l * 9 + n] = f2bf(p[n] * wv[n] * inv);
    }
    __syncthreads();

    // ---- MFMA over this chunk's K-slice (9 k-steps of 32) ----
#pragma unroll
    for (int ks = 0; ks < 9; ++ks) {
      bf16x8 av[4], bv[5];
#pragma unroll
      for (int i = 0; i < 4; ++i)
        av[i] = *reinterpret_cast<const bf16x8*>(
            Wcb + (size_t)(w * 64 + i * 16 + l15) * CN_ + ch * KCH_ + ks * 32 + 8 * lhi);
#pragma unroll
      for (int nf = 0; nf < 5; ++nf)
        bv[nf] = *reinterpret_cast<const bf16x8*>(
            &vbuf[nf * 16 + l15][ks * 32 + 8 * lhi]);
#pragma unroll
      for (int i = 0; i < 4; ++i)
#pragma unroll
        for (int nf = 0; nf < 5; ++nf)
          acc[i][nf] = __builtin_amdgcn_mfma_f32_16x16x32_bf16(
              av[i], bv[nf], acc[i][nf], 0, 0, 0);
    }
    __syncthreads();
  }

  // ---- epilogue: BN2 + ReLU + residual ----
#pragma unroll
  for (int i = 0; i < 4; ++i) {
#pragma unroll
    for (int r = 0; r < 4; ++r) {
      int o = w * 64 + i * 16 + lhi * 4 + r;
      float sA = A2[o], sB = B2[o];
#pragma unroll
      for (int nf = 0; nf < 5; ++nf) {
        float val = fmaf(acc[i][nf][r], sA, sB);
        val = fmaxf(val, 0.f);
        size_t idx = ((size_t)b * C2_ + o) * HW_ + y * W_ + nf * 16 + l15;
        out[idx] = x[idx] + val;
      }
    }
  }
}

extern "C" void kernel_launch(void* const* d_in, const int* in_sizes, int n_in,
                              void* d_out, int out_size, void* d_ws, size_t ws_size,
                              hipStream_t stream) {
  (void)in_sizes; (void)n_in; (void)out_size; (void)ws_size;
  const float* x   = (const float*)d_in[0];
  const float* W1  = (const float*)d_in[1];
  const float* g1  = (const float*)d_in[2];
  const float* b1  = (const float*)d_in[3];
  const float* m1  = (const float*)d_in[4];
  const float* v1  = (const float*)d_in[5];
  const float* Wg  = (const float*)d_in[6];
  const float* bg  = (const float*)d_in[7];
  const float* gg  = (const float*)d_in[8];
  const float* bgw = (const float*)d_in[9];
  const float* mg  = (const float*)d_in[10];
  const float* vg  = (const float*)d_in[11];
  const float* Wc  = (const float*)d_in[12];
  const float* bc  = (const float*)d_in[13];
  const float* g2  = (const float*)d_in[14];
  const float* b2  = (const float*)d_in[15];
  const float* m2  = (const float*)d_in[16];
  const float* v2  = (const float*)d_in[17];
  float* outp = (float*)d_out;

  // workspace layout (bytes):
  //   h   : bf16 [8][128][6400]   13,107,200
  //   Wcb : bf16 [256][1152]         589,824
  //   A2,B2: f32 [256] each            2,048
  char* ws = (char*)d_ws;
  unsigned short* h   = (unsigned short*)ws;
  unsigned short* Wcb = (unsigned short*)(ws + 13107200);
  float*          A2  = (float*)(ws + 13107200 + 589824);
  float*          B2  = A2 + C2_;

  k0_prep<<<dim3((C2_ * CN_ + 255) / 256), 256, 0, stream>>>(
      Wc, bc, g2, b2, m2, v2, Wcb, A2, B2);

  dim3 grid1(HW_ / 128, B_);
  k1_cv1<<<grid1, 256, 0, stream>>>(x, W1, g1, b1, m1, v1, h);

  dim3 grid2(H_, B_);
  k2f<<<grid2, 256, 0, stream>>>(h, Wg, bg, gg, bgw, mg, vg,
                                 Wcb, A2, B2, x, outp);
}